// Round 5
// baseline (19285.838 us; speedup 1.0000x reference)
//
#include <hip/hip_runtime.h>
#include <hip/hip_bf16.h>

#define B_ 64
#define T_ 512
#define O_ 512
#define N_ 2048
#define NWG 128
#define EPSF 1e-5f

typedef __attribute__((ext_vector_type(8))) short short8v;
typedef __attribute__((ext_vector_type(4))) float f32x4;
typedef unsigned short u16;
typedef unsigned long long u64;

__device__ __forceinline__ u16 f2bf(float f) {
    union { float f; unsigned u; } v; v.f = f;
    unsigned r = v.u + 0x7fffu + ((v.u >> 16) & 1u);   // RNE
    return (u16)(r >> 16);
}

// sc1 (agent-scope, LLC-coherent) helpers — no cache-wide fences anywhere
__device__ __forceinline__ u64 ldg_sc1_u64(const void* p) {
    return __hip_atomic_load((const u64*)p, __ATOMIC_RELAXED, __HIP_MEMORY_SCOPE_AGENT);
}
__device__ __forceinline__ void stg_sc1_u32(unsigned* p, unsigned v) {
    __hip_atomic_store(p, v, __ATOMIC_RELAXED, __HIP_MEMORY_SCOPE_AGENT);
}
__device__ __forceinline__ void atom_add_f32(float* p, float v) {
    __hip_atomic_fetch_add(p, v, __ATOMIC_RELAXED, __HIP_MEMORY_SCOPE_AGENT);
}

// ---------- init: W fp32 [1024][2048] -> wt bf16 [2048 col][1024 k] ----------
__global__ void k_init_wt(const float* __restrict__ W, u16* __restrict__ wt) {
    __shared__ u16 tile[64][65];
    const int tk = (blockIdx.x >> 5) * 64;
    const int tn = (blockIdx.x & 31) * 64;
    const int r = threadIdx.x >> 6, c = threadIdx.x & 63;
#pragma unroll
    for (int i = 0; i < 16; ++i)
        tile[r + 4 * i][c] = f2bf(W[(size_t)(tk + r + 4 * i) * N_ + tn + c]);
    __syncthreads();
#pragma unroll
    for (int i = 0; i < 16; ++i)
        wt[(size_t)(tn + r + 4 * i) * 1024 + tk + c] = tile[c][r + 4 * i];
}

// ---------- init: zero per-step stats + the two barrier counters ----------
__global__ void k_zero(float* __restrict__ stats, unsigned* __restrict__ cnt) {
    int gid = blockIdx.x * 256 + threadIdx.x;
    if (gid < T_ * 2 * B_) stats[gid] = 0.f;       // 512 steps x 64 rows x (S,Q)
    if (gid == 0) { cnt[0] = 0; cnt[32] = 0; }
}

// ---------- persistent LN-LSTM ----------
__global__ __launch_bounds__(256, 1)
void k_persist(const float* __restrict__ x, const u16* __restrict__ wt,
               const float* __restrict__ bias, const float* __restrict__ lnw,
               const float* __restrict__ lnb, const float* __restrict__ hx,
               const float* __restrict__ cx, u16* hbuf, float* stats,
               unsigned* cnt, float* __restrict__ out) {
    __shared__ char wlds[32768];    // 16 owned cols x 1024 k bf16, XOR-swizzled
    __shared__ float sstat[128];    // final (S,Q) per batch row

    const int tid = threadIdx.x, wgid = blockIdx.x;
    const int w = tid >> 6, l = tid & 63;
    const int rl = l & 15, kg = l >> 4;
    const int m = rl >> 2;                    // gate index of this lane's col
    const int row = 16 * w + rl;              // A-row this lane loads
    const int row0 = 16 * w + kg * 4;         // first C-row of this lane's acc
    const int base_o = 4 * wgid + (rl & 3);   // o-column this lane group owns
    const int col = base_o + 512 * m;         // flattened [4][512] col of this lane

    unsigned* cntA = cnt;          // stats-ready counter
    unsigned* cntB = cnt + 32;     // h-ready counter (separate cache line)

    // ---- stage W slice (remapped cols) into LDS, once ----
    for (int it = 0; it < 8; ++it) {
        int idx = tid + 256 * it;
        int c = idx >> 7, k0 = (idx & 127) * 8;
        int n = 4 * wgid + (c & 3) + 512 * (c >> 2);
        short8v v = *(const short8v*)(wt + (size_t)n * 1024 + k0);
        *(short8v*)(wlds + c * 2048 + ((k0 * 2) ^ ((c & 7) << 4))) = v;
    }

    // ---- per-lane constants & state ----
    const float bcol = bias[col];
    const float lnw_c = lnw[col], lnb_c = lnb[col];
    float creg[4];
#pragma unroll
    for (int j = 0; j < 4; ++j) creg[j] = cx[base_o];

    // ---- h0 into hbuf slot 0 (sc1, packed u32) ----
    {
        int idx = wgid * 256 + tid;           // wgs 0..63 cover 16384 u32 writes
        if (idx < 16384) {
            int r = idx >> 8, op = (idx & 255) * 2;
            unsigned hp = (unsigned)f2bf(hx[op]) | ((unsigned)f2bf(hx[op + 1]) << 16);
            stg_sc1_u32((unsigned*)(hbuf + (r << 9) + op), hp);
        }
    }

    // ---- barrier pieces ----
    auto arrive = [&](unsigned* c) {
        asm volatile("s_waitcnt vmcnt(0)" ::: "memory");
        __syncthreads();
        if (tid == 0)
            __hip_atomic_fetch_add(c, 1u, __ATOMIC_RELAXED, __HIP_MEMORY_SCOPE_AGENT);
    };
    auto wait = [&](unsigned* c, unsigned tgt) {
        if (tid == 0) {
            while (__hip_atomic_load(c, __ATOMIC_RELAXED,
                                     __HIP_MEMORY_SCOPE_AGENT) < tgt) {}
        }
        __syncthreads();
    };

    // ---- GEMM halves ----
    auto xhalf = [&](int t, f32x4& c0, f32x4& c1) {
        const float* xrowf = x + (size_t)row * (T_ * 512) + (size_t)t * 512;
#pragma unroll
        for (int kc = 0; kc < 16; ++kc) {
            int kloc = kc * 32 + kg * 8;
            float4 u0 = *(const float4*)(xrowf + kloc);
            float4 u1 = *(const float4*)(xrowf + kloc + 4);
            short8v a;
            a[0] = (short)f2bf(u0.x); a[1] = (short)f2bf(u0.y);
            a[2] = (short)f2bf(u0.z); a[3] = (short)f2bf(u0.w);
            a[4] = (short)f2bf(u1.x); a[5] = (short)f2bf(u1.y);
            a[6] = (short)f2bf(u1.z); a[7] = (short)f2bf(u1.w);
            short8v bb = *(const short8v*)(wlds + rl * 2048 + ((kloc * 2) ^ ((rl & 7) << 4)));
            if (kc & 1) c1 = __builtin_amdgcn_mfma_f32_16x16x32_bf16(a, bb, c1, 0, 0, 0);
            else        c0 = __builtin_amdgcn_mfma_f32_16x16x32_bf16(a, bb, c0, 0, 0, 0);
        }
    };
    auto hhalf = [&](const u16* hread, f32x4& c0, f32x4& c1) {
        const u16* hrow = hread + (row << 9);
#pragma unroll
        for (int kc = 0; kc < 16; ++kc) {
            int kloc = kc * 32 + kg * 8;
            short8v a = *(const short8v*)(hrow + kloc);   // normal cached load
            short8v bb = *(const short8v*)(wlds + rl * 2048 +
                           (((kloc + 512) * 2) ^ ((rl & 7) << 4)));
            if (kc & 1) c1 = __builtin_amdgcn_mfma_f32_16x16x32_bf16(a, bb, c1, 0, 0, 0);
            else        c0 = __builtin_amdgcn_mfma_f32_16x16x32_bf16(a, bb, c0, 0, 0, 0);
        }
    };

    // init barrier: wlds (via syncthreads) + h0 visible; overlap with xhalf(0)
    arrive(cntB);
    f32x4 xa0 = {0.f,0.f,0.f,0.f}, xa1 = {0.f,0.f,0.f,0.f};
    xhalf(0, xa0, xa1);
    wait(cntB, NWG);

    for (int t = 0; t < T_; ++t) {
        // ============ phase 1: finish GEMM with h-half ============
        f32x4 ha0 = {0.f,0.f,0.f,0.f}, ha1 = {0.f,0.f,0.f,0.f};
        hhalf(hbuf + (size_t)t * (B_ * O_), ha0, ha1);
        f32x4 acc = (xa0 + xa1) + (ha0 + ha1);

        float v[4], sj[4], qj[4];
#pragma unroll
        for (int j = 0; j < 4; ++j) {
            v[j] = acc[j] + bcol;
            sj[j] = v[j]; qj[j] = v[j] * v[j];
        }
#pragma unroll
        for (int mm = 1; mm < 16; mm <<= 1) {
#pragma unroll
            for (int j = 0; j < 4; ++j) {
                sj[j] += __shfl_xor(sj[j], mm);
                qj[j] += __shfl_xor(qj[j], mm);
            }
        }
        float* st = stats + t * (2 * B_);
        if (rl == 0) {
#pragma unroll
            for (int j = 0; j < 4; ++j) {
                atom_add_f32(st + (row0 + j) * 2, sj[j]);
                atom_add_f32(st + (row0 + j) * 2 + 1, qj[j]);
            }
        }

        arrive(cntA);
        wait(cntA, (unsigned)NWG * (t + 1));    // stats(t) final

        // ============ phase 2: LN + gates + state (all from registers) ============
        if (tid < B_) {
            union { u64 q; float f[2]; } p;
            p.q = ldg_sc1_u64(st + tid * 2);
            sstat[tid * 2] = p.f[0]; sstat[tid * 2 + 1] = p.f[1];
        }
        __syncthreads();

        float h[4];
#pragma unroll
        for (int j = 0; j < 4; ++j) {
            float S = sstat[(row0 + j) * 2], Q = sstat[(row0 + j) * 2 + 1];
            float mu = S * (1.0f / 2048.0f);
            float var = Q * (1.0f / 2048.0f) - mu * mu;
            float rstd = rsqrtf(var + EPSF);
            float nv = (v[j] - mu) * rstd * lnw_c + lnb_c;
            // gather the 4 gate values for (row0+j, base_o) across lanes rl^4, rl^8
            float p4 = __shfl_xor(nv, 4);
            float ge = (m & 1) ? p4 : nv;
            float go = (m & 1) ? nv : p4;
            float p8e = __shfl_xor(ge, 8);
            float p8o = __shfl_xor(go, 8);
            float g0 = (m & 2) ? p8e : ge;
            float g2 = (m & 2) ? ge : p8e;
            float g1 = (m & 2) ? p8o : go;
            float g3 = (m & 2) ? go : p8o;
            float ig = 1.f / (1.f + __expf(-g0));
            float fg = 1.f / (1.f + __expf(-g1));
            float og = 1.f / (1.f + __expf(-g2));
            float e2 = __expf(-2.f * fabsf(g3));
            float th = copysignf((1.f - e2) / (1.f + e2), g3);
            float cc = fg * creg[j] + ig * th;
            creg[j] = cc;
            h[j] = og * cc;
        }
        if (rl < 4) {
#pragma unroll
            for (int j = 0; j < 4; ++j)
                __builtin_nontemporal_store(h[j],
                    out + (size_t)(row0 + j) * (T_ * O_) + (size_t)t * O_ + base_o);
        }

        if (t == T_ - 1) break;

        // h(t+1-read slot): pack pairs, sc1 store to the fresh rotating buffer
        u16* hW = hbuf + (size_t)(t + 1) * (B_ * O_);
#pragma unroll
        for (int j = 0; j < 4; ++j) {
            float hp = __shfl_xor(h[j], 1);
            if (rl < 4 && !(rl & 1)) {
                unsigned pk = (unsigned)f2bf(h[j]) | ((unsigned)f2bf(hp) << 16);
                stg_sc1_u32((unsigned*)(hW + ((row0 + j) << 9) + base_o), pk);
            }
        }

        arrive(cntB);
        xa0 = f32x4{0.f,0.f,0.f,0.f}; xa1 = f32x4{0.f,0.f,0.f,0.f};
        xhalf(t + 1, xa0, xa1);                 // overlap with h-barrier wait
        wait(cntB, (unsigned)NWG * (t + 2));    // h(t+1) visible
    }
}

extern "C" void kernel_launch(void* const* d_in, const int* in_sizes, int n_in,
                              void* d_out, int out_size, void* d_ws, size_t ws_size,
                              hipStream_t stream) {
    const float* x    = (const float*)d_in[0];
    const float* W    = (const float*)d_in[1];
    const float* bias = (const float*)d_in[2];
    const float* lnw  = (const float*)d_in[3];
    const float* lnb  = (const float*)d_in[4];
    const float* hx   = (const float*)d_in[5];
    const float* cx   = (const float*)d_in[6];
    float* out = (float*)d_out;

    char* ws = (char*)d_ws;
    u16*      wt    = (u16*)ws;                       // 4 MiB
    u16*      hbuf  = (u16*)(ws + 4194304);           // 32 MiB (512 rotating h bufs)
    float*    stats = (float*)(ws + 37748736);        // 256 KiB (512 x 64 x 2)
    unsigned* cnt   = (unsigned*)(ws + 38010880);     // 256 B

    k_init_wt<<<512, 256, 0, stream>>>(W, wt);
    k_zero<<<256, 256, 0, stream>>>(stats, cnt);
    k_persist<<<NWG, 256, 0, stream>>>(x, wt, bias, lnw, lnb, hx, cx,
                                       hbuf, stats, cnt, out);
}

// Round 6
// 5518.494 us; speedup vs baseline: 3.4948x; 3.4948x over previous
//
#include <hip/hip_runtime.h>
#include <hip/hip_bf16.h>

#define B_ 64
#define T_ 512
#define O_ 512
#define N_ 2048
#define NWG 128
#define EPSF 1e-5f

typedef __attribute__((ext_vector_type(8))) short short8v;
typedef __attribute__((ext_vector_type(4))) float f32x4;
typedef unsigned short u16;
typedef unsigned long long u64;

__device__ __forceinline__ u16 f2bf(float f) {
    union { float f; unsigned u; } v; v.f = f;
    unsigned r = v.u + 0x7fffu + ((v.u >> 16) & 1u);   // RNE
    return (u16)(r >> 16);
}

// sc1 (agent-scope, LLC-coherent) helpers — relaxed, no cache-wide fences, no RMW
__device__ __forceinline__ u64 ldg_sc1_u64(const void* p) {
    return __hip_atomic_load((const u64*)p, __ATOMIC_RELAXED, __HIP_MEMORY_SCOPE_AGENT);
}
__device__ __forceinline__ float ldg_sc1_f32(const float* p) {
    return __hip_atomic_load(p, __ATOMIC_RELAXED, __HIP_MEMORY_SCOPE_AGENT);
}
__device__ __forceinline__ void stg_sc1_f32(float* p, float v) {
    __hip_atomic_store(p, v, __ATOMIC_RELAXED, __HIP_MEMORY_SCOPE_AGENT);
}
__device__ __forceinline__ void stg_sc1_u32(unsigned* p, unsigned v) {
    __hip_atomic_store(p, v, __ATOMIC_RELAXED, __HIP_MEMORY_SCOPE_AGENT);
}

// ---------- init: W fp32 [1024][2048] -> wt bf16 [2048 col][1024 k] ----------
__global__ void k_init_wt(const float* __restrict__ W, u16* __restrict__ wt) {
    __shared__ u16 tile[64][65];
    const int tk = (blockIdx.x >> 5) * 64;
    const int tn = (blockIdx.x & 31) * 64;
    const int r = threadIdx.x >> 6, c = threadIdx.x & 63;
#pragma unroll
    for (int i = 0; i < 16; ++i)
        tile[r + 4 * i][c] = f2bf(W[(size_t)(tk + r + 4 * i) * N_ + tn + c]);
    __syncthreads();
#pragma unroll
    for (int i = 0; i < 16; ++i)
        wt[(size_t)(tn + r + 4 * i) * 1024 + tk + c] = tile[c][r + 4 * i];
}

__global__ void k_zero_flags(unsigned* flags) {
    stg_sc1_u32(flags + threadIdx.x, 0u);
}

// ---------- persistent LN-LSTM ----------
__global__ __launch_bounds__(256, 1)
void k_persist(const float* __restrict__ x, const u16* __restrict__ wt,
               const float* __restrict__ bias, const float* __restrict__ lnw,
               const float* __restrict__ lnb, const float* __restrict__ hx,
               const float* __restrict__ cx, u16* hbuf, float* comb,
               float* statsp, unsigned* flags, float* __restrict__ out) {
    __shared__ char wlds[32768];    // 16 cols x 1024 k bf16, XOR-swizzled
    __shared__ float sred[4];

    const int tid = threadIdx.x, wgid = blockIdx.x;
    const int n0 = wgid * 16;
    const int w = tid >> 6, l = tid & 63;
    const int rl = l & 15, kg = l >> 4;
    const int row = 16 * w + rl;
    const int row0 = 16 * w + kg * 4;

    // stage W slice into LDS (once)
    for (int it = 0; it < 8; ++it) {
        int idx = tid + 256 * it;
        int col = idx >> 7, k0 = (idx & 127) * 8;
        short8v v = *(const short8v*)(wt + (size_t)(n0 + col) * 1024 + k0);
        *(short8v*)(wlds + col * 2048 + ((k0 * 2) ^ ((col & 7) << 4))) = v;
    }

    // phase-2 identity: wg-pair owns one batch row
    const int b2 = wgid >> 1;
    const int o = (wgid & 1) * 256 + tid;
    float lw0 = lnw[o], lw1 = lnw[512 + o], lw2 = lnw[1024 + o], lw3 = lnw[1536 + o];
    float lb0 = lnb[o], lb1 = lnb[512 + o], lb2 = lnb[1024 + o], lb3 = lnb[1536 + o];
    float creg = cx[o];
    {   // h0 into hbuf slot 0 (sc1, packed pairs)
        float h0v = hx[o];
        float hn = __shfl_xor(h0v, 1);
        if (!(tid & 1)) {
            unsigned hp = (unsigned)f2bf(h0v) | ((unsigned)f2bf(hn) << 16);
            stg_sc1_u32((unsigned*)(hbuf + b2 * O_ + o), hp);
        }
    }
    const float bcol = bias[n0 + rl];

    // ---- one-hop flat barrier: parallel flag stores + lane-per-flag all-poll ----
    auto arrive = [&](unsigned g) {
        asm volatile("s_waitcnt vmcnt(0)" ::: "memory");   // sc1 stores at LLC
        __syncthreads();
        if (tid == 0) stg_sc1_u32(flags + wgid, g);
    };
    auto wait = [&](unsigned g) {
        if (tid < NWG) {
            while (__hip_atomic_load(flags + tid, __ATOMIC_RELAXED,
                                     __HIP_MEMORY_SCOPE_AGENT) < g) {}
        }
        __syncthreads();
    };

    // x-half chunk: 8 of 16 K-slices, fp32 load + convert (hides under barrier wait)
    auto xhalf8 = [&](int t, int kc0, f32x4& c0, f32x4& c1) {
        const float* xrowf = x + (size_t)row * (T_ * 512) + (size_t)t * 512;
#pragma unroll
        for (int kc = 0; kc < 8; ++kc) {
            int kloc = (kc + kc0) * 32 + kg * 8;
            float4 u0 = *(const float4*)(xrowf + kloc);
            float4 u1 = *(const float4*)(xrowf + kloc + 4);
            short8v a;
            a[0] = (short)f2bf(u0.x); a[1] = (short)f2bf(u0.y);
            a[2] = (short)f2bf(u0.z); a[3] = (short)f2bf(u0.w);
            a[4] = (short)f2bf(u1.x); a[5] = (short)f2bf(u1.y);
            a[6] = (short)f2bf(u1.z); a[7] = (short)f2bf(u1.w);
            short8v bb = *(const short8v*)(wlds + rl * 2048 + ((kloc * 2) ^ ((rl & 7) << 4)));
            if (kc & 1) c1 = __builtin_amdgcn_mfma_f32_16x16x32_bf16(a, bb, c1, 0, 0, 0);
            else        c0 = __builtin_amdgcn_mfma_f32_16x16x32_bf16(a, bb, c0, 0, 0, 0);
        }
    };
    // h-half: normal cached loads from the rotating hbuf slot (fresh addrs, L2-shared)
    auto hhalf = [&](const u16* hread, f32x4& c0, f32x4& c1) {
        const u16* hrow = hread + (row << 9);
#pragma unroll
        for (int kc = 0; kc < 16; ++kc) {
            int kloc = kc * 32 + kg * 8;
            short8v a = *(const short8v*)(hrow + kloc);
            short8v bb = *(const short8v*)(wlds + rl * 2048 +
                           (((kloc + 512) * 2) ^ ((rl & 7) << 4)));
            if (kc & 1) c1 = __builtin_amdgcn_mfma_f32_16x16x32_bf16(a, bb, c1, 0, 0, 0);
            else        c0 = __builtin_amdgcn_mfma_f32_16x16x32_bf16(a, bb, c0, 0, 0, 0);
        }
    };

    unsigned gen = 1;
    arrive(gen);                       // wlds local (syncthreads inside); h0 at LLC
    f32x4 xa0 = {0.f,0.f,0.f,0.f}, xa1 = {0.f,0.f,0.f,0.f};
    xhalf8(0, 0, xa0, xa1);
    xhalf8(0, 8, xa0, xa1);
    wait(gen); gen++;

    for (int t = 0; t < T_; ++t) {
        // ============ phase 1: finish GEMM with h-half ============
        f32x4 ha0 = {0.f,0.f,0.f,0.f}, ha1 = {0.f,0.f,0.f,0.f};
        hhalf(hbuf + (size_t)t * (B_ * O_), ha0, ha1);
        f32x4 acc = (xa0 + xa1) + (ha0 + ha1);

        float sj[4], qj[4];
#pragma unroll
        for (int j = 0; j < 4; ++j) {
            float v = acc[j] + bcol;
            stg_sc1_f32(comb + (size_t)(row0 + j) * N_ + (n0 + rl), v);
            sj[j] = v; qj[j] = v * v;
        }
#pragma unroll
        for (int m = 1; m < 16; m <<= 1) {
#pragma unroll
            for (int j = 0; j < 4; ++j) {
                sj[j] += __shfl_xor(sj[j], m);
                qj[j] += __shfl_xor(qj[j], m);
            }
        }
        if (rl == 0) {
#pragma unroll
            for (int j = 0; j < 4; ++j) {
                size_t sidx = ((size_t)(row0 + j) * NWG + wgid) * 2;
                stg_sc1_f32(statsp + sidx, sj[j]);
                stg_sc1_f32(statsp + sidx + 1, qj[j]);
            }
        }

        arrive(gen);                                // stats+comb release
        if (t < T_ - 1) {                           // overlap: first x-chunk of t+1
            xa0 = f32x4{0.f,0.f,0.f,0.f}; xa1 = f32x4{0.f,0.f,0.f,0.f};
            xhalf8(t + 1, 0, xa0, xa1);
        }
        wait(gen); gen++;                           // stats(t) final

        // ============ phase 2: LN + gates + state update ============
        float s = 0.f, q = 0.f;
        if (tid < NWG) {
            union { u64 q64; float f[2]; } p;
            p.q64 = ldg_sc1_u64(statsp + ((size_t)b2 * NWG + tid) * 2);
            s = p.f[0]; q = p.f[1];
        }
#pragma unroll
        for (int m = 32; m > 0; m >>= 1) {
            s += __shfl_down(s, m);
            q += __shfl_down(q, m);
        }
        if (tid < NWG && (tid & 63) == 0) {
            sred[(tid >> 6) * 2] = s;
            sred[(tid >> 6) * 2 + 1] = q;
        }
        __syncthreads();
        float S = sred[0] + sred[2], Q = sred[1] + sred[3];
        float mu = S * (1.0f / 2048.0f);
        float var = Q * (1.0f / 2048.0f) - mu * mu;
        float rstd = rsqrtf(var + EPSF);

        const float* cb = comb + (size_t)b2 * N_ + o;
        float n0v = (ldg_sc1_f32(cb)        - mu) * rstd * lw0 + lb0;
        float n1v = (ldg_sc1_f32(cb + 512)  - mu) * rstd * lw1 + lb1;
        float n2v = (ldg_sc1_f32(cb + 1024) - mu) * rstd * lw2 + lb2;
        float n3v = (ldg_sc1_f32(cb + 1536) - mu) * rstd * lw3 + lb3;
        float ig = 1.f / (1.f + __expf(-n0v));
        float fg = 1.f / (1.f + __expf(-n1v));
        float og = 1.f / (1.f + __expf(-n2v));
        float e2 = __expf(-2.f * fabsf(n3v));
        float th = copysignf((1.f - e2) / (1.f + e2), n3v);
        creg = fg * creg + ig * th;
        float h = og * creg;
        __builtin_nontemporal_store(h, out + (size_t)b2 * (T_ * O_) + (size_t)t * O_ + o);

        if (t == T_ - 1) break;                     // no one consumes the last h

        // h(t+1) into the fresh rotating slot (sc1, packed pairs)
        {
            u16* hW = hbuf + (size_t)(t + 1) * (B_ * O_);
            float hn = __shfl_xor(h, 1);
            if (!(tid & 1)) {
                unsigned hp = (unsigned)f2bf(h) | ((unsigned)f2bf(hn) << 16);
                stg_sc1_u32((unsigned*)(hW + b2 * O_ + o), hp);
            }
        }

        arrive(gen);                                // h release
        xhalf8(t + 1, 8, xa0, xa1);                 // overlap: second x-chunk of t+1
        wait(gen); gen++;                           // h(t+1) visible
    }
}

extern "C" void kernel_launch(void* const* d_in, const int* in_sizes, int n_in,
                              void* d_out, int out_size, void* d_ws, size_t ws_size,
                              hipStream_t stream) {
    const float* x    = (const float*)d_in[0];
    const float* W    = (const float*)d_in[1];
    const float* bias = (const float*)d_in[2];
    const float* lnw  = (const float*)d_in[3];
    const float* lnb  = (const float*)d_in[4];
    const float* hx   = (const float*)d_in[5];
    const float* cx   = (const float*)d_in[6];
    float* out = (float*)d_out;

    char* ws = (char*)d_ws;
    u16*      wt     = (u16*)ws;                      // 4 MiB
    u16*      hbuf   = (u16*)(ws + 4194304);          // 32 MiB (512 rotating h slots)
    float*    statsp = (float*)(ws + 37748736);       // 64 KiB [64 rows][128 wgs] f2
    float*    comb   = (float*)(ws + 37814272);       // 512 KiB
    unsigned* flags  = (unsigned*)(ws + 38338560);    // 1 KiB
    // total 38339584 B < proven ws floor (38797312 B from round 4)

    k_init_wt<<<512, 256, 0, stream>>>(W, wt);
    k_zero_flags<<<1, 256, 0, stream>>>(flags);
    k_persist<<<NWG, 256, 0, stream>>>(x, wt, bias, lnw, lnb, hx, cx,
                                       hbuf, comb, statsp, flags, out);
}